// Round 2
// baseline (293.460 us; speedup 1.0000x reference)
//
#include <hip/hip_runtime.h>

// K-best MIMO detector, B=8192, M=16, S=8, 16-QAM (ns=16), k=64.
// One wave (64 threads) per batch item; lane == candidate slot.
// Math: Cholesky whitening == eigh-isqrt whitening (W^H W = s^-1 invariance);
// R from Cholesky of permuted Gram == QR's R up to diagonal phase (cancels in |resid|^2).
// Preprocessing in fp64 so R/ybar are ~exact; fp32 tree search mirrors reference rounding.

#define BIGF 1e30f
#define CLIPV 20.0f

__device__ __forceinline__ void tri_decode(int t, int &a, int &b) {
    // t -> (a,b) with 0 <= b <= a, t = a(a+1)/2 + b
    int a0 = (int)((sqrtf(8.0f * (float)t + 1.0f) - 1.0f) * 0.5f);
    while ((a0 + 1) * (a0 + 2) / 2 <= t) ++a0;
    while ((a0 * (a0 + 1)) / 2 > t) --a0;
    a = a0;
    b = t - (a0 * (a0 + 1)) / 2;
}

__global__ __launch_bounds__(64) void kbest16_kernel(
    const float* __restrict__ y_re, const float* __restrict__ y_im,
    const float* __restrict__ h_re, const float* __restrict__ h_im,
    const float* __restrict__ s_re, const float* __restrict__ s_im,
    const float* __restrict__ p_re, const float* __restrict__ p_im,
    float* __restrict__ out)
{
    __shared__ double A[16][16][2];   // s -> Cholesky L (lower, diag real)
    __shared__ double W[16][9][2];    // [h | y] -> whitened (L^{-1}[h|y])
    __shared__ double G[8][8][2];     // permuted Gram -> L8 (lower)
    __shared__ double bv[8][2];       // hs^H yw -> ybar (in place)
    __shared__ double nrm[8];
    __shared__ float Rm[8][8][2];     // R = L8^H (upper, diag real > 0), fp32 for search
    __shared__ float yb[8][2];        // ybar fp32
    __shared__ float pts[16][2];
    __shared__ float rp[16][2];       // rii * points, per level
    __shared__ float sel_d[64];
    __shared__ unsigned sel_s[64];
    __shared__ int perm[8];
    __shared__ int invp[8];

    const int lane = threadIdx.x;
    const int b = blockIdx.x;

    const float* sre = s_re + (size_t)b * 256;
    const float* simm = s_im + (size_t)b * 256;
    const float* hre = h_re + (size_t)b * 128;
    const float* him = h_im + (size_t)b * 128;

    // ---- stage inputs (coalesced) ----
    #pragma unroll
    for (int t = 0; t < 4; ++t) {
        int e = lane + 64 * t;
        A[e >> 4][e & 15][0] = (double)sre[e];
        A[e >> 4][e & 15][1] = (double)simm[e];
    }
    #pragma unroll
    for (int t = 0; t < 2; ++t) {
        int e = lane + 64 * t;
        W[e >> 3][e & 7][0] = (double)hre[e];
        W[e >> 3][e & 7][1] = (double)him[e];
    }
    if (lane < 16) {
        W[lane][8][0] = (double)y_re[(size_t)b * 16 + lane];
        W[lane][8][1] = (double)y_im[(size_t)b * 16 + lane];
        pts[lane][0] = p_re[lane];
        pts[lane][1] = p_im[lane];
    }
    __syncthreads();

    // ---- Cholesky of s: 16x16, lower, diag real (fp64) ----
    for (int j = 0; j < 16; ++j) {
        double djj = sqrt(A[j][j][0]);
        double inv = 1.0 / djj;
        __syncthreads();
        if (lane == 0) A[j][j][0] = djj;
        int i = j + 1 + lane;
        if (i < 16) { A[i][j][0] *= inv; A[i][j][1] *= inv; }
        __syncthreads();
        int n = 15 - j, tot = (n * (n + 1)) / 2;
        for (int t = lane; t < tot; t += 64) {
            int a, c; tri_decode(t, a, c);
            int ii = j + 1 + a, kk = j + 1 + c;
            double lir = A[ii][j][0], lii = A[ii][j][1];
            double lkr = A[kk][j][0], lki = A[kk][j][1];
            // A[ii][kk] -= L[ii][j] * conj(L[kk][j])
            A[ii][kk][0] -= lir * lkr + lii * lki;
            A[ii][kk][1] -= lii * lkr - lir * lki;
        }
        __syncthreads();
    }

    // ---- forward solve L * W = [h | y] (fp64) ----
    for (int r = 0; r < 16; ++r) {
        double inv = 1.0 / A[r][r][0];
        if (lane < 9) { W[r][lane][0] *= inv; W[r][lane][1] *= inv; }
        __syncthreads();
        int rem = (15 - r) * 9;
        for (int t = lane; t < rem; t += 64) {
            int i = r + 1 + t / 9, c = t % 9;
            double lr = A[i][r][0], li = A[i][r][1];
            double wr = W[r][c][0], wi = W[r][c][1];
            W[i][c][0] -= lr * wr - li * wi;
            W[i][c][1] -= lr * wi + li * wr;
        }
        __syncthreads();
    }

    // ---- column norms (= h^H s^-1 h diag) + stable descending argsort ----
    if (lane < 8) {
        double s = 0.0;
        #pragma unroll
        for (int m = 0; m < 16; ++m)
            s += W[m][lane][0] * W[m][lane][0] + W[m][lane][1] * W[m][lane][1];
        nrm[lane] = s;
    }
    __syncthreads();
    if (lane < 8) {
        double ni = nrm[lane];
        int rank = 0;
        #pragma unroll
        for (int jj = 0; jj < 8; ++jj) {
            double nj = nrm[jj];
            rank += (nj > ni || (nj == ni && jj < lane)) ? 1 : 0;
        }
        perm[rank] = lane;   // sorted pos -> original col
        invp[lane] = rank;   // original col -> sorted pos
    }
    __syncthreads();

    // ---- permuted Gram (lower tri, 36) + rhs bs = hs^H yw (8), fp64 ----
    if (lane < 44) {
        int a, c;
        int isG = lane < 36;
        if (isG) tri_decode(lane, a, c); else { a = lane - 36; c = 0; }
        int pa = perm[a];
        int pc = isG ? perm[c] : 8;
        double ar = 0.0, ai = 0.0;
        #pragma unroll
        for (int m = 0; m < 16; ++m) {
            double xr = W[m][pa][0], xi = W[m][pa][1];
            double yr = W[m][pc][0], yi = W[m][pc][1];
            ar += xr * yr + xi * yi;   // conj(x)*y
            ai += xr * yi - xi * yr;
        }
        if (isG) { G[a][c][0] = ar; G[a][c][1] = ai; }
        else { bv[a][0] = ar; bv[a][1] = ai; }
    }
    __syncthreads();

    // ---- Cholesky of Gram: 8x8 (fp64) ----
    for (int j = 0; j < 8; ++j) {
        double djj = sqrt(G[j][j][0]);
        double inv = 1.0 / djj;
        __syncthreads();
        if (lane == 0) G[j][j][0] = djj;
        int i = j + 1 + lane;
        if (i < 8) { G[i][j][0] *= inv; G[i][j][1] *= inv; }
        __syncthreads();
        int n = 7 - j, tot = (n * (n + 1)) / 2;
        if (lane < tot) {
            int a, c; tri_decode(lane, a, c);
            int ii = j + 1 + a, kk = j + 1 + c;
            double lir = G[ii][j][0], lii = G[ii][j][1];
            double lkr = G[kk][j][0], lki = G[kk][j][1];
            G[ii][kk][0] -= lir * lkr + lii * lki;
            G[ii][kk][1] -= lii * lkr - lir * lki;
        }
        __syncthreads();
    }
    // R = L8^H, cast to fp32
    if (lane < 36) {
        int a, c; tri_decode(lane, a, c);   // a >= c
        Rm[c][a][0] = (float)G[a][c][0];
        Rm[c][a][1] = (float)(-G[a][c][1]);
    }

    // ---- ybar = L8^{-1} bs (forward solve in place, fp64) ----
    for (int r = 0; r < 8; ++r) {
        if (lane == 0) {
            double inv = 1.0 / G[r][r][0];
            bv[r][0] *= inv; bv[r][1] *= inv;
        }
        __syncthreads();
        int i = r + 1 + lane;
        if (i < 8) {
            double lr = G[i][r][0], li = G[i][r][1];
            double wr = bv[r][0], wi = bv[r][1];
            bv[i][0] -= lr * wr - li * wi;
            bv[i][1] -= lr * wi + li * wr;
        }
        __syncthreads();
    }
    if (lane < 8) { yb[lane][0] = (float)bv[lane][0]; yb[lane][1] = (float)bv[lane][1]; }
    __syncthreads();

    // ---- K-best search (fp32); lane == candidate. Level 7 (root expansion): ----
    float dist; unsigned syms;
    if (lane < 16) {
        float r77 = Rm[7][7][0];
        float er = yb[7][0] - r77 * pts[lane][0];
        float ei = yb[7][1] - r77 * pts[lane][1];
        dist = er * er + ei * ei;
        syms = (unsigned)lane << 28;
    } else {
        dist = BIGF;   // 1e30 + x == 1e30 exactly in fp32 -> displaced once 256 real cands exist
        syms = 0u;
    }

    for (int lev = 6; lev >= 0; --lev) {
        __syncthreads();
        if (lane < 16) {
            float rii = Rm[lev][lev][0];   // real > 0 by construction
            rp[lane][0] = rii * pts[lane][0];
            rp[lane][1] = rii * pts[lane][1];
        }
        __syncthreads();

        // partial = sum_{j>lev} R[lev][j] * x_j
        float pr = 0.0f, pi = 0.0f;
        for (int j = lev + 1; j < 8; ++j) {
            int sj = (syms >> (4 * j)) & 15;
            float xr = pts[sj][0], xi = pts[sj][1];
            float rr = Rm[lev][j][0], ri = Rm[lev][j][1];
            pr += rr * xr - ri * xi;
            pi += rr * xi + ri * xr;
        }
        float tr = yb[lev][0] - pr, ti = yb[lev][1] - pi;

        float d[16];
        #pragma unroll
        for (int p = 0; p < 16; ++p) {
            float er = tr - rp[p][0], ei = ti - rp[p][1];
            d[p] = dist + (er * er + ei * ei);
        }

        // ---- exact top-64-of-1024: binary search on fp32 bit patterns ----
        float mnl = d[0];
        #pragma unroll
        for (int p = 1; p < 16; ++p) mnl = fminf(mnl, d[p]);
        float gmn = mnl, gmx = mnl;   // gmx = max of lane-minima >= 64th smallest
        #pragma unroll
        for (int off = 32; off > 0; off >>= 1) {
            gmn = fminf(gmn, __shfl_xor(gmn, off));
            gmx = fmaxf(gmx, __shfl_xor(gmx, off));
        }
        unsigned lo = __float_as_uint(gmn) + 1u;
        unsigned hi = __float_as_uint(gmx) + 1u;
        bool exact = false;
        unsigned Bb = 0u;
        while (lo < hi) {
            unsigned mid = (lo + hi) >> 1;
            float Tf = __uint_as_float(mid);
            int c = 0;
            #pragma unroll
            for (int p = 0; p < 16; ++p) c += (d[p] < Tf) ? 1 : 0;
            #pragma unroll
            for (int off = 32; off > 0; off >>= 1) c += __shfl_xor(c, off);
            if (c == 64) { Bb = mid; exact = true; break; }
            if (c > 64) hi = mid; else lo = mid + 1u;
        }
        float Tlt, Teq;
        if (exact) { Tlt = __uint_as_float(Bb); Teq = -1.0f; }       // exactly 64 strictly below
        else       { Tlt = __uint_as_float(lo - 1u); Teq = Tlt; }   // ties at the 64th value

        int cl = 0, ce = 0;
        #pragma unroll
        for (int p = 0; p < 16; ++p) {
            cl += (d[p] < Tlt) ? 1 : 0;
            ce += (d[p] == Teq) ? 1 : 0;
        }
        // packed exclusive scan over lanes (16-bit fields; totals <= 1024)
        int v = cl | (ce << 16);
        int sc = v;
        #pragma unroll
        for (int off = 1; off < 64; off <<= 1) {
            int t = __shfl_up(sc, off);
            if (lane >= off) sc += t;
        }
        int excl = sc - v;
        int tots = __shfl(sc, 63);
        int offL = excl & 0xffff;
        int offE = excl >> 16;
        int totL = tots & 0xffff;

        unsigned base = syms & ~(15u << (4 * lev));
        int slot = offL;
        #pragma unroll
        for (int p = 0; p < 16; ++p) {
            if (d[p] < Tlt) {
                sel_d[slot] = d[p];
                sel_s[slot] = base | ((unsigned)p << (4 * lev));
                ++slot;
            }
        }
        int eslot = totL + offE;   // index-ordered tie fill, matches lax.top_k
        #pragma unroll
        for (int p = 0; p < 16; ++p) {
            if (d[p] == Teq) {
                if (eslot < 64) {
                    sel_d[eslot] = d[p];
                    sel_s[eslot] = base | ((unsigned)p << (4 * lev));
                }
                ++eslot;
            }
        }
        __syncthreads();
        dist = sel_d[lane];
        syms = sel_s[lane];
    }
    __syncthreads();

    // ---- LLRs: lanes 0..31 each own one (orig symbol s, bit j); coalesced write ----
    if (lane < 32) {
        int s = lane >> 2, jj = lane & 3;
        int sh = 4 * invp[s] + (3 - jj);   // bit of symbol at sorted position invp[s], MSB first
        float d0 = BIGF, d1 = BIGF;
        for (int c = 0; c < 64; ++c) {
            float dc = sel_d[c];
            unsigned cs = sel_s[c];
            if ((cs >> sh) & 1u) d1 = fminf(d1, dc);
            else d0 = fminf(d0, dc);
        }
        float llr = d0 - d1;
        llr = fminf(fmaxf(llr, -CLIPV), CLIPV);
        out[(size_t)b * 32 + lane] = llr;
    }
}

extern "C" void kernel_launch(void* const* d_in, const int* in_sizes, int n_in,
                              void* d_out, int out_size, void* d_ws, size_t ws_size,
                              hipStream_t stream) {
    (void)n_in; (void)d_ws; (void)ws_size; (void)out_size;
    const float* y_re = (const float*)d_in[0];
    const float* y_im = (const float*)d_in[1];
    const float* h_re = (const float*)d_in[2];
    const float* h_im = (const float*)d_in[3];
    const float* s_re = (const float*)d_in[4];
    const float* s_im = (const float*)d_in[5];
    const float* p_re = (const float*)d_in[6];
    const float* p_im = (const float*)d_in[7];
    // d_in[8] = k (fixed 64 per problem setup)
    int B = in_sizes[0] / 16;
    kbest16_kernel<<<dim3(B), dim3(64), 0, stream>>>(
        y_re, y_im, h_re, h_im, s_re, s_im, p_re, p_im, (float*)d_out);
}

// Round 4
// 240.723 us; speedup vs baseline: 1.2191x; 1.2191x over previous
//
#include <hip/hip_runtime.h>

// K-best MIMO detector, B=8192, M=16, S=8, 16-QAM (ns=16), k=64.
// One wave (64 lanes) per batch item, 4 waves per 256-thread block, each wave
// fully independent: NO __syncthreads anywhere. Intra-wave LDS handoff relies on
// wave lockstep + in-order DS retirement; WSYNC() = s_waitcnt lgkmcnt(0) with a
// compiler memory fence orders write->read across lanes.
// Math: Cholesky whitening == eigh-isqrt whitening (W^H W = s^-1 invariance);
// R from Cholesky of permuted Gram == QR's R up to diag phase (cancels in |resid|^2).
// Preprocessing fp64 (=> R/ybar ~exact); fp32 tree search mirrors reference rounding.

#define BIGF 1e30f
#define CLIPV 20.0f
#define WPB 4          // waves per block
#define WAVE_DBL 864   // doubles of LDS per wave (6912 B)

#define WSYNC() asm volatile("s_waitcnt lgkmcnt(0)" ::: "memory")

__device__ __forceinline__ void tri_decode(int t, int &a, int &b) {
    // t -> (a,b) with 0 <= b <= a, t = a(a+1)/2 + b
    int a0 = (int)((sqrtf(8.0f * (float)t + 1.0f) - 1.0f) * 0.5f);
    while ((a0 + 1) * (a0 + 2) / 2 <= t) ++a0;
    while ((a0 * (a0 + 1)) / 2 > t) --a0;
    a = a0;
    b = t - (a0 * (a0 + 1)) / 2;
}

__device__ __forceinline__ int mbcnt64(unsigned long long m) {
    int r = __builtin_amdgcn_mbcnt_lo((unsigned)m, 0);
    return __builtin_amdgcn_mbcnt_hi((unsigned)(m >> 32), r);
}

__global__ __launch_bounds__(256, 5) void kbest16_kernel(
    const float* __restrict__ y_re, const float* __restrict__ y_im,
    const float* __restrict__ h_re, const float* __restrict__ h_im,
    const float* __restrict__ s_re, const float* __restrict__ s_im,
    const float* __restrict__ p_re, const float* __restrict__ p_im,
    float* __restrict__ out)
{
    __shared__ double smem[WPB * WAVE_DBL];   // 27648 B/block -> 5 blocks/CU

    const int tid = threadIdx.x;
    const int wid = tid >> 6;
    const int lane = tid & 63;
    const int b = blockIdx.x * WPB + wid;

    double* wb = &smem[(size_t)wid * WAVE_DBL];
    // Phase-1 regions:
    double (*A)[17][2]  = (double(*)[17][2])wb;          // [0,544)  16x17x2 (pad row->+4 banks)
    double (*Wm)[10][2] = (double(*)[10][2])(wb + 544);  // [544,864) 16x10x2
    // Phase-2 regions (alias the dead A region):
    double (*G)[9][2] = (double(*)[9][2])wb;             // [0,144)
    double (*bv)[2]   = (double(*)[2])(wb + 144);        // [144,160)
    double* nrm       = wb + 160;                        // [160,168)
    int* perm         = (int*)(wb + 168);                // [168,172)
    int* invp         = (int*)(wb + 172);                // [172,176)
    float (*Rm)[9][2] = (float(*)[9][2])(wb + 176);      // [176,248)
    float (*yb)[2]    = (float(*)[2])(wb + 248);         // [248,256)
    unsigned long long* sel = (unsigned long long*)(wb + 256); // [256,320)

    const float* sre = s_re + (size_t)b * 256;
    const float* sim = s_im + (size_t)b * 256;
    const float* hre = h_re + (size_t)b * 128;
    const float* him = h_im + (size_t)b * 128;

    // ---- stage inputs (coalesced) ----
    #pragma unroll
    for (int t = 0; t < 4; ++t) {
        int e = lane + 64 * t;
        A[e >> 4][e & 15][0] = (double)sre[e];
        A[e >> 4][e & 15][1] = (double)sim[e];
    }
    #pragma unroll
    for (int t = 0; t < 2; ++t) {
        int e = lane + 64 * t;
        Wm[e >> 3][e & 7][0] = (double)hre[e];
        Wm[e >> 3][e & 7][1] = (double)him[e];
    }
    if (lane < 16) {
        Wm[lane][8][0] = (double)y_re[(size_t)b * 16 + lane];
        Wm[lane][8][1] = (double)y_im[(size_t)b * 16 + lane];
    }
    float plr = p_re[lane & 15];   // per-lane point copy for dynamic gather via shuffle
    float pli = p_im[lane & 15];
    WSYNC();

    // ---- Cholesky of s: 16x16, lower, diag real (fp64) ----
    for (int j = 0; j < 16; ++j) {
        double djj = sqrt(A[j][j][0]);     // broadcast read (pre-update in program order)
        double inv = 1.0 / djj;
        if (lane == 0) A[j][j][0] = djj;
        int i = j + 1 + lane;
        if (i < 16) { A[i][j][0] *= inv; A[i][j][1] *= inv; }
        WSYNC();
        int n = 15 - j, tot = (n * (n + 1)) / 2;
        for (int t = lane; t < tot; t += 64) {
            int a, c; tri_decode(t, a, c);
            int ii = j + 1 + a, kk = j + 1 + c;
            double lir = A[ii][j][0], lii = A[ii][j][1];
            double lkr = A[kk][j][0], lki = A[kk][j][1];
            A[ii][kk][0] -= lir * lkr + lii * lki;   // -= L[ii][j]*conj(L[kk][j])
            A[ii][kk][1] -= lii * lkr - lir * lki;
        }
        WSYNC();
    }

    // ---- forward solve L * W = [h | y] (fp64) ----
    for (int r = 0; r < 16; ++r) {
        double inv = 1.0 / A[r][r][0];
        if (lane < 9) { Wm[r][lane][0] *= inv; Wm[r][lane][1] *= inv; }
        WSYNC();
        int rem = (15 - r) * 9;
        for (int t = lane; t < rem; t += 64) {
            int i = r + 1 + t / 9, c = t % 9;
            double lr = A[i][r][0], li = A[i][r][1];
            double wr = Wm[r][c][0], wi = Wm[r][c][1];
            Wm[i][c][0] -= lr * wr - li * wi;
            Wm[i][c][1] -= lr * wi + li * wr;
        }
        WSYNC();
    }
    // A is dead from here; its region is reused (G/bv/nrm/perm/invp/Rm/yb/sel).

    // ---- column norms + stable descending argsort ----
    if (lane < 8) {
        double s = 0.0;
        #pragma unroll
        for (int m = 0; m < 16; ++m)
            s += Wm[m][lane][0] * Wm[m][lane][0] + Wm[m][lane][1] * Wm[m][lane][1];
        nrm[lane] = s;
    }
    WSYNC();
    if (lane < 8) {
        double ni = nrm[lane];
        int rank = 0;
        #pragma unroll
        for (int jj = 0; jj < 8; ++jj) {
            double nj = nrm[jj];
            rank += (nj > ni || (nj == ni && jj < lane)) ? 1 : 0;
        }
        perm[rank] = lane;
        invp[lane] = rank;
    }
    WSYNC();

    // ---- permuted Gram (lower tri, 36) + rhs bs = hs^H yw (8), fp64 ----
    if (lane < 44) {
        int a, c;
        int isG = lane < 36;
        if (isG) tri_decode(lane, a, c); else { a = lane - 36; c = 0; }
        int pa = perm[a];
        int pc = isG ? perm[c] : 8;
        double ar = 0.0, ai = 0.0;
        #pragma unroll
        for (int m = 0; m < 16; ++m) {
            double xr = Wm[m][pa][0], xi = Wm[m][pa][1];
            double yr = Wm[m][pc][0], yi = Wm[m][pc][1];
            ar += xr * yr + xi * yi;   // conj(x)*y
            ai += xr * yi - xi * yr;
        }
        if (isG) { G[a][c][0] = ar; G[a][c][1] = ai; }
        else { bv[a][0] = ar; bv[a][1] = ai; }
    }
    WSYNC();

    // ---- Cholesky of Gram: 8x8 (fp64) ----
    for (int j = 0; j < 8; ++j) {
        double djj = sqrt(G[j][j][0]);
        double inv = 1.0 / djj;
        if (lane == 0) G[j][j][0] = djj;
        int i = j + 1 + lane;
        if (i < 8) { G[i][j][0] *= inv; G[i][j][1] *= inv; }
        WSYNC();
        int n = 7 - j, tot = (n * (n + 1)) / 2;
        if (lane < tot) {
            int a, c; tri_decode(lane, a, c);
            int ii = j + 1 + a, kk = j + 1 + c;
            double lir = G[ii][j][0], lii = G[ii][j][1];
            double lkr = G[kk][j][0], lki = G[kk][j][1];
            G[ii][kk][0] -= lir * lkr + lii * lki;
            G[ii][kk][1] -= lii * lkr - lir * lki;
        }
        WSYNC();
    }
    // R = L8^H (fp32) into W-dead region
    if (lane < 36) {
        int a, c; tri_decode(lane, a, c);   // a >= c
        Rm[c][a][0] = (float)G[a][c][0];
        Rm[c][a][1] = (float)(-G[a][c][1]);
    }
    // ---- ybar = L8^{-1} bs (fp64, in place) ----
    for (int r = 0; r < 8; ++r) {
        if (lane == 0) {
            double inv = 1.0 / G[r][r][0];
            bv[r][0] *= inv; bv[r][1] *= inv;
        }
        WSYNC();
        int i = r + 1 + lane;
        if (i < 8) {
            double lr = G[i][r][0], li = G[i][r][1];
            double wr = bv[r][0], wi = bv[r][1];
            bv[i][0] -= lr * wr - li * wi;
            bv[i][1] -= lr * wi + li * wr;
        }
        WSYNC();
    }
    if (lane < 8) { yb[lane][0] = (float)bv[lane][0]; yb[lane][1] = (float)bv[lane][1]; }
    WSYNC();

    // ---- K-best search (fp32). Level 7 root expansion: ----
    float dist; unsigned syms;
    {
        float r77 = Rm[7][7][0];
        float er = yb[7][0] - r77 * p_re[lane & 15];
        float ei = yb[7][1] - r77 * p_im[lane & 15];
        float dr = er * er + ei * ei;
        dist = (lane < 16) ? dr : BIGF;   // BIGF + x == BIGF exactly in fp32
        syms = (lane < 16) ? ((unsigned)lane << 28) : 0u;
    }

    for (int lev = 6; lev >= 0; --lev) {
        // partial = sum_{j>lev} R[lev][j] * x_j  (points gathered via wave shuffle)
        float pr = 0.0f, pim = 0.0f;
        for (int j = lev + 1; j < 8; ++j) {
            int sj = (syms >> (4 * j)) & 15;
            float xr = __shfl(plr, sj);
            float xi = __shfl(pli, sj);
            float rr = Rm[lev][j][0], ri = Rm[lev][j][1];
            pr += rr * xr - ri * xi;
            pim += rr * xi + ri * xr;
        }
        float rii = Rm[lev][lev][0];   // real > 0 by construction
        float tr = yb[lev][0] - pr, ti = yb[lev][1] - pim;

        float d[16];
        #pragma unroll
        for (int p = 0; p < 16; ++p) {
            float er = tr - rii * p_re[p];   // p_re[p]: uniform scalar-load constants
            float ei = ti - rii * p_im[p];
            d[p] = dist + (er * er + ei * ei);
        }

        // ---- exact top-64-of-1024: binary search on fp32 bit patterns,
        //      counting via ballot+popcount (no dependent shuffle chains) ----
        float mnl = d[0];
        #pragma unroll
        for (int p = 1; p < 16; ++p) mnl = fminf(mnl, d[p]);
        float gmn = mnl, gmx = mnl;   // gmx = max of lane-minima >= 64th smallest
        #pragma unroll
        for (int off = 32; off > 0; off >>= 1) {
            gmn = fminf(gmn, __shfl_xor(gmn, off));
            gmx = fmaxf(gmx, __shfl_xor(gmx, off));
        }
        unsigned lo = __float_as_uint(gmn) + 1u;
        unsigned hi = __float_as_uint(gmx) + 1u;
        bool exact = false;
        unsigned Bb = 0u;
        while (lo < hi) {
            unsigned mid = (lo + hi) >> 1;
            float Tf = __uint_as_float(mid);
            int c = 0;
            #pragma unroll
            for (int p = 0; p < 16; ++p)
                c += __popcll(__ballot(d[p] < Tf));
            if (c == 64) { Bb = mid; exact = true; break; }
            if (c > 64) hi = mid; else lo = mid + 1u;
        }
        float Tlt, Teq;
        if (exact) { Tlt = __uint_as_float(Bb); Teq = -1.0f; }      // exactly 64 strictly below
        else       { Tlt = __uint_as_float(lo - 1u); Teq = Tlt; }  // ties at the 64th value

        // pass 1: offsets via mbcnt (lane-major order == reference index order)
        int offL = 0, offE = 0, totL = 0;
        #pragma unroll
        for (int p = 0; p < 16; ++p) {
            unsigned long long mlt = __ballot(d[p] < Tlt);
            unsigned long long meq = __ballot(d[p] == Teq);
            offL += mbcnt64(mlt);
            offE += mbcnt64(meq);
            totL += __popcll(mlt);
        }
        // pass 2: scatter survivors into sel[64] (packed dist|syms)
        unsigned base = syms & ~(15u << (4 * lev));
        int slot = offL;
        #pragma unroll
        for (int p = 0; p < 16; ++p) {
            if (d[p] < Tlt) {
                unsigned ns = base | ((unsigned)p << (4 * lev));
                sel[slot] = ((unsigned long long)ns << 32) | (unsigned long long)__float_as_uint(d[p]);
                ++slot;
            }
        }
        int eslot = totL + offE;   // index-ordered tie fill, matches lax.top_k
        #pragma unroll
        for (int p = 0; p < 16; ++p) {
            if (d[p] == Teq) {
                if (eslot < 64) {
                    unsigned ns = base | ((unsigned)p << (4 * lev));
                    sel[eslot] = ((unsigned long long)ns << 32) | (unsigned long long)__float_as_uint(d[p]);
                }
                ++eslot;
            }
        }
        WSYNC();
        unsigned long long v = sel[lane];
        dist = __uint_as_float((unsigned)v);
        syms = (unsigned)(v >> 32);
    }

    // ---- LLRs: lanes 0..31 each own (orig symbol s, bit j); coalesced write ----
    if (lane < 32) {
        int s = lane >> 2, jj = lane & 3;
        int sh = 4 * invp[s] + (3 - jj) + 32;   // bit position within packed syms (high word)
        float d0a = BIGF, d0b = BIGF, d1a = BIGF, d1b = BIGF;
        for (int c = 0; c < 64; c += 2) {
            unsigned long long v1 = sel[c];       // broadcast reads
            unsigned long long v2 = sel[c + 1];
            float f1 = __uint_as_float((unsigned)v1);
            float f2 = __uint_as_float((unsigned)v2);
            bool b1 = (v1 >> sh) & 1ull;
            bool b2 = (v2 >> sh) & 1ull;
            d1a = fminf(d1a, b1 ? f1 : BIGF);
            d0a = fminf(d0a, b1 ? BIGF : f1);
            d1b = fminf(d1b, b2 ? f2 : BIGF);
            d0b = fminf(d0b, b2 ? BIGF : f2);
        }
        float d0 = fminf(d0a, d0b), d1 = fminf(d1a, d1b);
        float llr = d0 - d1;
        llr = fminf(fmaxf(llr, -CLIPV), CLIPV);
        out[(size_t)b * 32 + lane] = llr;
    }
}

extern "C" void kernel_launch(void* const* d_in, const int* in_sizes, int n_in,
                              void* d_out, int out_size, void* d_ws, size_t ws_size,
                              hipStream_t stream) {
    (void)n_in; (void)d_ws; (void)ws_size; (void)out_size;
    const float* y_re = (const float*)d_in[0];
    const float* y_im = (const float*)d_in[1];
    const float* h_re = (const float*)d_in[2];
    const float* h_im = (const float*)d_in[3];
    const float* s_re = (const float*)d_in[4];
    const float* s_im = (const float*)d_in[5];
    const float* p_re = (const float*)d_in[6];
    const float* p_im = (const float*)d_in[7];
    // d_in[8] = k (fixed 64 per problem setup)
    int B = in_sizes[0] / 16;
    kbest16_kernel<<<dim3(B / WPB), dim3(64 * WPB), 0, stream>>>(
        y_re, y_im, h_re, h_im, s_re, s_im, p_re, p_im, (float*)d_out);
}

// Round 6
// 239.377 us; speedup vs baseline: 1.2259x; 1.0056x over previous
//
#include <hip/hip_runtime.h>

// K-best MIMO detector, B=8192, M=16, S=8, 16-QAM (ns=16), k=64.
// One wave (64 lanes) per batch item, 4 waves per 256-thread block, each wave
// fully independent: NO __syncthreads anywhere. Intra-wave LDS handoff relies on
// wave lockstep + in-order DS retirement; WSYNC() = s_waitcnt lgkmcnt(0) with a
// compiler memory fence orders write->read across lanes.
// Math: Cholesky whitening == eigh-isqrt whitening (W^H W = s^-1 invariance);
// R from Cholesky of permuted Gram == QR's R up to diag phase (cancels in |resid|^2).
// Preprocessing fp64 (=> R/ybar ~exact); fp32 tree search mirrors reference rounding.
//
// R4 post-mortem: __launch_bounds__(256,5) forced VGPR->48 and spilled the search
// state to scratch (WRITE_SIZE 1MB->91MB, FETCH 13->65MB). (256,4) caps at 128
// VGPR: whole search state in registers, 4 blocks/CU honest occupancy.

#define BIGF 1e30f
#define CLIPV 20.0f
#define WPB 4          // waves per block
#define WAVE_DBL 864   // doubles of LDS per wave (6912 B)

#define WSYNC() asm volatile("s_waitcnt lgkmcnt(0)" ::: "memory")

__device__ __forceinline__ void tri_decode(int t, int &a, int &b) {
    // t -> (a,b) with 0 <= b <= a, t = a(a+1)/2 + b
    int a0 = (int)((sqrtf(8.0f * (float)t + 1.0f) - 1.0f) * 0.5f);
    while ((a0 + 1) * (a0 + 2) / 2 <= t) ++a0;
    while ((a0 * (a0 + 1)) / 2 > t) --a0;
    a = a0;
    b = t - (a0 * (a0 + 1)) / 2;
}

__device__ __forceinline__ int mbcnt64(unsigned long long m) {
    int r = __builtin_amdgcn_mbcnt_lo((unsigned)m, 0);
    return __builtin_amdgcn_mbcnt_hi((unsigned)(m >> 32), r);
}

__global__ __launch_bounds__(256, 4) void kbest16_kernel(
    const float* __restrict__ y_re, const float* __restrict__ y_im,
    const float* __restrict__ h_re, const float* __restrict__ h_im,
    const float* __restrict__ s_re, const float* __restrict__ s_im,
    const float* __restrict__ p_re, const float* __restrict__ p_im,
    float* __restrict__ out)
{
    __shared__ double smem[WPB * WAVE_DBL];   // 27648 B/block

    const int tid = threadIdx.x;
    const int wid = tid >> 6;
    const int lane = tid & 63;
    const int b = blockIdx.x * WPB + wid;

    double* wb = &smem[(size_t)wid * WAVE_DBL];
    // Phase-1 regions:
    double (*A)[17][2]  = (double(*)[17][2])wb;          // [0,544)  16x17x2 (pad row->+4 banks)
    double (*Wm)[10][2] = (double(*)[10][2])(wb + 544);  // [544,864) 16x10x2
    // Phase-2 regions (alias the dead A region):
    double (*G)[9][2] = (double(*)[9][2])wb;             // [0,144)
    double (*bv)[2]   = (double(*)[2])(wb + 144);        // [144,160)
    double* nrm       = wb + 160;                        // [160,168)
    int* perm         = (int*)(wb + 168);                // [168,172)
    int* invp         = (int*)(wb + 172);                // [172,176)
    float (*Rm)[9][2] = (float(*)[9][2])(wb + 176);      // [176,248)
    float (*yb)[2]    = (float(*)[2])(wb + 248);         // [248,256)
    unsigned long long* sel = (unsigned long long*)(wb + 256); // [256,320)

    const float* sre = s_re + (size_t)b * 256;
    const float* sim = s_im + (size_t)b * 256;
    const float* hre = h_re + (size_t)b * 128;
    const float* him = h_im + (size_t)b * 128;

    // ---- stage inputs (coalesced) ----
    #pragma unroll
    for (int t = 0; t < 4; ++t) {
        int e = lane + 64 * t;
        A[e >> 4][e & 15][0] = (double)sre[e];
        A[e >> 4][e & 15][1] = (double)sim[e];
    }
    #pragma unroll
    for (int t = 0; t < 2; ++t) {
        int e = lane + 64 * t;
        Wm[e >> 3][e & 7][0] = (double)hre[e];
        Wm[e >> 3][e & 7][1] = (double)him[e];
    }
    if (lane < 16) {
        Wm[lane][8][0] = (double)y_re[(size_t)b * 16 + lane];
        Wm[lane][8][1] = (double)y_im[(size_t)b * 16 + lane];
    }
    float plr = p_re[lane & 15];   // per-lane point copy for dynamic gather via shuffle
    float pli = p_im[lane & 15];
    WSYNC();

    // ---- Cholesky of s: 16x16, lower, diag real (fp64) ----
    for (int j = 0; j < 16; ++j) {
        double djj = sqrt(A[j][j][0]);     // broadcast read (pre-update in program order)
        double inv = 1.0 / djj;
        if (lane == 0) A[j][j][0] = djj;
        int i = j + 1 + lane;
        if (i < 16) { A[i][j][0] *= inv; A[i][j][1] *= inv; }
        WSYNC();
        int n = 15 - j, tot = (n * (n + 1)) / 2;
        for (int t = lane; t < tot; t += 64) {
            int a, c; tri_decode(t, a, c);
            int ii = j + 1 + a, kk = j + 1 + c;
            double lir = A[ii][j][0], lii = A[ii][j][1];
            double lkr = A[kk][j][0], lki = A[kk][j][1];
            A[ii][kk][0] -= lir * lkr + lii * lki;   // -= L[ii][j]*conj(L[kk][j])
            A[ii][kk][1] -= lii * lkr - lir * lki;
        }
        WSYNC();
    }

    // ---- forward solve L * W = [h | y] (fp64) ----
    for (int r = 0; r < 16; ++r) {
        double inv = 1.0 / A[r][r][0];
        if (lane < 9) { Wm[r][lane][0] *= inv; Wm[r][lane][1] *= inv; }
        WSYNC();
        int rem = (15 - r) * 9;
        for (int t = lane; t < rem; t += 64) {
            int i = r + 1 + t / 9, c = t % 9;
            double lr = A[i][r][0], li = A[i][r][1];
            double wr = Wm[r][c][0], wi = Wm[r][c][1];
            Wm[i][c][0] -= lr * wr - li * wi;
            Wm[i][c][1] -= lr * wi + li * wr;
        }
        WSYNC();
    }
    // A is dead from here; its region is reused (G/bv/nrm/perm/invp/Rm/yb/sel).

    // ---- column norms + stable descending argsort ----
    if (lane < 8) {
        double s = 0.0;
        #pragma unroll
        for (int m = 0; m < 16; ++m)
            s += Wm[m][lane][0] * Wm[m][lane][0] + Wm[m][lane][1] * Wm[m][lane][1];
        nrm[lane] = s;
    }
    WSYNC();
    if (lane < 8) {
        double ni = nrm[lane];
        int rank = 0;
        #pragma unroll
        for (int jj = 0; jj < 8; ++jj) {
            double nj = nrm[jj];
            rank += (nj > ni || (nj == ni && jj < lane)) ? 1 : 0;
        }
        perm[rank] = lane;
        invp[lane] = rank;
    }
    WSYNC();

    // ---- permuted Gram (lower tri, 36) + rhs bs = hs^H yw (8), fp64 ----
    if (lane < 44) {
        int a, c;
        int isG = lane < 36;
        if (isG) tri_decode(lane, a, c); else { a = lane - 36; c = 0; }
        int pa = perm[a];
        int pc = isG ? perm[c] : 8;
        double ar = 0.0, ai = 0.0;
        #pragma unroll
        for (int m = 0; m < 16; ++m) {
            double xr = Wm[m][pa][0], xi = Wm[m][pa][1];
            double yr = Wm[m][pc][0], yi = Wm[m][pc][1];
            ar += xr * yr + xi * yi;   // conj(x)*y
            ai += xr * yi - xi * yr;
        }
        if (isG) { G[a][c][0] = ar; G[a][c][1] = ai; }
        else { bv[a][0] = ar; bv[a][1] = ai; }
    }
    WSYNC();

    // ---- Cholesky of Gram: 8x8 (fp64) ----
    for (int j = 0; j < 8; ++j) {
        double djj = sqrt(G[j][j][0]);
        double inv = 1.0 / djj;
        if (lane == 0) G[j][j][0] = djj;
        int i = j + 1 + lane;
        if (i < 8) { G[i][j][0] *= inv; G[i][j][1] *= inv; }
        WSYNC();
        int n = 7 - j, tot = (n * (n + 1)) / 2;
        if (lane < tot) {
            int a, c; tri_decode(lane, a, c);
            int ii = j + 1 + a, kk = j + 1 + c;
            double lir = G[ii][j][0], lii = G[ii][j][1];
            double lkr = G[kk][j][0], lki = G[kk][j][1];
            G[ii][kk][0] -= lir * lkr + lii * lki;
            G[ii][kk][1] -= lii * lkr - lir * lki;
        }
        WSYNC();
    }
    // R = L8^H (fp32) into W-dead region
    if (lane < 36) {
        int a, c; tri_decode(lane, a, c);   // a >= c
        Rm[c][a][0] = (float)G[a][c][0];
        Rm[c][a][1] = (float)(-G[a][c][1]);
    }
    // ---- ybar = L8^{-1} bs (fp64, in place) ----
    for (int r = 0; r < 8; ++r) {
        if (lane == 0) {
            double inv = 1.0 / G[r][r][0];
            bv[r][0] *= inv; bv[r][1] *= inv;
        }
        WSYNC();
        int i = r + 1 + lane;
        if (i < 8) {
            double lr = G[i][r][0], li = G[i][r][1];
            double wr = bv[r][0], wi = bv[r][1];
            bv[i][0] -= lr * wr - li * wi;
            bv[i][1] -= lr * wi + li * wr;
        }
        WSYNC();
    }
    if (lane < 8) { yb[lane][0] = (float)bv[lane][0]; yb[lane][1] = (float)bv[lane][1]; }
    WSYNC();

    // ---- K-best search (fp32). Level 7 root expansion: ----
    float dist; unsigned syms;
    {
        float r77 = Rm[7][7][0];
        float er = yb[7][0] - r77 * p_re[lane & 15];
        float ei = yb[7][1] - r77 * p_im[lane & 15];
        float dr = er * er + ei * ei;
        dist = (lane < 16) ? dr : BIGF;   // BIGF + x == BIGF exactly in fp32
        syms = (lane < 16) ? ((unsigned)lane << 28) : 0u;
    }

    for (int lev = 6; lev >= 0; --lev) {
        // partial = sum_{j>lev} R[lev][j] * x_j  (points gathered via wave shuffle)
        float pr = 0.0f, pim = 0.0f;
        for (int j = lev + 1; j < 8; ++j) {
            int sj = (syms >> (4 * j)) & 15;
            float xr = __shfl(plr, sj);
            float xi = __shfl(pli, sj);
            float rr = Rm[lev][j][0], ri = Rm[lev][j][1];
            pr += rr * xr - ri * xi;
            pim += rr * xi + ri * xr;
        }
        float rii = Rm[lev][lev][0];   // real > 0 by construction
        float tr = yb[lev][0] - pr, ti = yb[lev][1] - pim;

        float d[16];
        #pragma unroll
        for (int p = 0; p < 16; ++p) {
            float er = tr - rii * p_re[p];   // p_re[p]: uniform scalar-load constants
            float ei = ti - rii * p_im[p];
            d[p] = dist + (er * er + ei * ei);
        }

        // ---- exact top-64-of-1024: binary search on fp32 bit patterns,
        //      counting via ballot+popcount (no dependent shuffle chains) ----
        float mnl = d[0];
        #pragma unroll
        for (int p = 1; p < 16; ++p) mnl = fminf(mnl, d[p]);
        float gmn = mnl, gmx = mnl;   // gmx = max of lane-minima >= 64th smallest
        #pragma unroll
        for (int off = 32; off > 0; off >>= 1) {
            gmn = fminf(gmn, __shfl_xor(gmn, off));
            gmx = fmaxf(gmx, __shfl_xor(gmx, off));
        }
        unsigned lo = __float_as_uint(gmn) + 1u;
        unsigned hi = __float_as_uint(gmx) + 1u;
        bool exact = false;
        unsigned Bb = 0u;
        while (lo < hi) {
            unsigned mid = (lo + hi) >> 1;
            float Tf = __uint_as_float(mid);
            int c = 0;
            #pragma unroll
            for (int p = 0; p < 16; ++p)
                c += __popcll(__ballot(d[p] < Tf));
            if (c == 64) { Bb = mid; exact = true; break; }
            if (c > 64) hi = mid; else lo = mid + 1u;
        }
        float Tlt, Teq;
        if (exact) { Tlt = __uint_as_float(Bb); Teq = -1.0f; }      // exactly 64 strictly below
        else       { Tlt = __uint_as_float(lo - 1u); Teq = Tlt; }  // ties at the 64th value

        // pass 1: offsets via mbcnt (lane-major order == reference index order)
        int offL = 0, offE = 0, totL = 0;
        #pragma unroll
        for (int p = 0; p < 16; ++p) {
            unsigned long long mlt = __ballot(d[p] < Tlt);
            unsigned long long meq = __ballot(d[p] == Teq);
            offL += mbcnt64(mlt);
            offE += mbcnt64(meq);
            totL += __popcll(mlt);
        }
        // pass 2: scatter survivors into sel[64] (packed dist|syms)
        unsigned base = syms & ~(15u << (4 * lev));
        int slot = offL;
        #pragma unroll
        for (int p = 0; p < 16; ++p) {
            if (d[p] < Tlt) {
                unsigned ns = base | ((unsigned)p << (4 * lev));
                sel[slot] = ((unsigned long long)ns << 32) | (unsigned long long)__float_as_uint(d[p]);
                ++slot;
            }
        }
        int eslot = totL + offE;   // index-ordered tie fill, matches lax.top_k
        #pragma unroll
        for (int p = 0; p < 16; ++p) {
            if (d[p] == Teq) {
                if (eslot < 64) {
                    unsigned ns = base | ((unsigned)p << (4 * lev));
                    sel[eslot] = ((unsigned long long)ns << 32) | (unsigned long long)__float_as_uint(d[p]);
                }
                ++eslot;
            }
        }
        WSYNC();
        unsigned long long v = sel[lane];
        dist = __uint_as_float((unsigned)v);
        syms = (unsigned)(v >> 32);
    }

    // ---- LLRs: lanes 0..31 each own (orig symbol s, bit j); coalesced write ----
    if (lane < 32) {
        int s = lane >> 2, jj = lane & 3;
        int sh = 4 * invp[s] + (3 - jj) + 32;   // bit position within packed syms (high word)
        float d0a = BIGF, d0b = BIGF, d1a = BIGF, d1b = BIGF;
        for (int c = 0; c < 64; c += 2) {
            unsigned long long v1 = sel[c];       // broadcast reads
            unsigned long long v2 = sel[c + 1];
            float f1 = __uint_as_float((unsigned)v1);
            float f2 = __uint_as_float((unsigned)v2);
            bool b1 = (v1 >> sh) & 1ull;
            bool b2 = (v2 >> sh) & 1ull;
            d1a = fminf(d1a, b1 ? f1 : BIGF);
            d0a = fminf(d0a, b1 ? BIGF : f1);
            d1b = fminf(d1b, b2 ? f2 : BIGF);
            d0b = fminf(d0b, b2 ? BIGF : f2);
        }
        float d0 = fminf(d0a, d0b), d1 = fminf(d1a, d1b);
        float llr = d0 - d1;
        llr = fminf(fmaxf(llr, -CLIPV), CLIPV);
        out[(size_t)b * 32 + lane] = llr;
    }
}

extern "C" void kernel_launch(void* const* d_in, const int* in_sizes, int n_in,
                              void* d_out, int out_size, void* d_ws, size_t ws_size,
                              hipStream_t stream) {
    (void)n_in; (void)d_ws; (void)ws_size; (void)out_size;
    const float* y_re = (const float*)d_in[0];
    const float* y_im = (const float*)d_in[1];
    const float* h_re = (const float*)d_in[2];
    const float* h_im = (const float*)d_in[3];
    const float* s_re = (const float*)d_in[4];
    const float* s_im = (const float*)d_in[5];
    const float* p_re = (const float*)d_in[6];
    const float* p_im = (const float*)d_in[7];
    // d_in[8] = k (fixed 64 per problem setup)
    int B = in_sizes[0] / 16;
    kbest16_kernel<<<dim3(B / WPB), dim3(64 * WPB), 0, stream>>>(
        y_re, y_im, h_re, h_im, s_re, s_im, p_re, p_im, (float*)d_out);
}